// Round 6
// baseline (532.889 us; speedup 1.0000x reference)
//
#include <hip/hip_runtime.h>
#include <hip/hip_bf16.h>

// ---------------------------------------------------------------------------
// GCN 2-layer forward, round 6.
// Key change: feature-split XCD-partitioned aggregation.
//  - Gather buffers stored chunk-transposed [8][N][16feats] bf16; agg block
//    b handles chunk b&7 -> XCD b&7 (round-robin heuristic). Per-XCD gather
//    working set = 1.6 MB < 4 MiB L2 -> gathers become L2 hits (was ~3.3 TB/s
//    L2-miss bound; round-1 vs round-5 showed agg time invariant to bytes).
//  - Rows pre-scaled by isd_src: out = isd_i*(sum_nbr scaled + scaled_self)+b
//    -> no per-edge weight gather. hbT scaled in-place by k_prep (cnt final
//    after scatter); h2T scaled in gemm2 epilogue.
//  - slot stored as ushort (N<65536): halves scatter writes + slot re-reads.
//  - agg1: 2 lanes per 32B row-chunk -> 32 edges per gather instruction;
//    agg2: 1 lane per 16B row-chunk -> 64 edges per instruction.
// ---------------------------------------------------------------------------

#define GCN_IN   128
#define GCN_H    128
#define GCN_OUT  64
#define CAP      64
#define OVF_CAP  65536
#define SCAT_BLOCKS 1024   // 8 partitions x 128 blocks

__device__ __forceinline__ ushort f2bf(float f) {     // fp32 -> bf16 RNE
    uint b = __float_as_uint(f);
    b = (b + 0x7FFFu + ((b >> 16) & 1u)) >> 16;
    return (ushort)b;
}
__device__ __forceinline__ float bf2f_lo(uint u) { return __uint_as_float(u << 16); }
__device__ __forceinline__ float bf2f_hi(uint u) { return __uint_as_float(u & 0xFFFF0000u); }

// ---------------- fused: [0,SCAT) = XCD-partitioned scatter, rest = GEMM1 ---
// GEMM1: hbT[8][N][16] (bf16, unscaled) = A_f32[M x 128] * B_f32[128 x 128]
__global__ __launch_bounds__(256) void k_fused1(
        const int* __restrict__ src, const int* __restrict__ dst,
        int* __restrict__ cnt, ushort* __restrict__ slot,
        int* __restrict__ ovfcnt, int2* __restrict__ ovf, int E,
        const float* __restrict__ A, const float* __restrict__ B,
        ushort* __restrict__ C, int M, int N) {
    __shared__ float At[32][68];   // At[k][m], pad 68 -> conflict-free b128
    __shared__ float Bs[32][64];
    const int tid = threadIdx.x;

    if (blockIdx.x < SCAT_BLOCKS) {
        const int part = blockIdx.x & 7;           // round-robin -> XCD part
        const int psz  = (N + 7) >> 3;
        const int lo   = part * psz;
        const int hi   = min(lo + psz, N);
        const int bip  = blockIdx.x >> 3;          // 0..127 within partition
        const int stride = (SCAT_BLOCKS >> 3) * 256;
        for (int e = bip * 256 + tid; e < E; e += stride) {
            int d = __builtin_nontemporal_load(dst + e);
            int s = __builtin_nontemporal_load(src + e);
            if (d >= lo && d < hi) {
                int pos = atomicAdd(&cnt[d], 1);
                if (pos < CAP) {
                    slot[(size_t)d * CAP + pos] = (ushort)s;  // L2-resident
                } else {
                    int q = atomicAdd(ovfcnt, 1);
                    if (q < OVF_CAP) ovf[q] = make_int2(d, s);
                }
            }
        }
        return;
    }

    // ---- GEMM1 part ----
    const int g = blockIdx.x - SCAT_BLOCKS;
    const int row0 = (g >> 1) * 64;
    const int col0 = (g & 1) * 64;
    const int tx = tid & 15;
    const int ty = tid >> 4;
    float acc[4][4] = {};

    for (int kb = 0; kb < 128; kb += 32) {
        #pragma unroll
        for (int t = 0; t < 2; ++t) {
            int f = tid * 4 + t * 1024;
            int r = f >> 5;
            int k = f & 31;
            float4 v = make_float4(0.f, 0.f, 0.f, 0.f);
            int gr = row0 + r;
            if (gr < M) v = *(const float4*)(A + (size_t)gr * 128 + kb + k);
            At[k + 0][r] = v.x;
            At[k + 1][r] = v.y;
            At[k + 2][r] = v.z;
            At[k + 3][r] = v.w;
        }
        #pragma unroll
        for (int t = 0; t < 2; ++t) {
            int f = tid * 4 + t * 1024;
            int r = f >> 6;
            int c = f & 63;
            *(float4*)&Bs[r][c] = *(const float4*)(B + (size_t)(kb + r) * 128 + col0 + c);
        }
        __syncthreads();
        #pragma unroll 8
        for (int k = 0; k < 32; ++k) {
            float4 a = *(const float4*)&At[k][ty * 4];
            float4 b = *(const float4*)&Bs[k][tx * 4];
            acc[0][0] += a.x * b.x; acc[0][1] += a.x * b.y; acc[0][2] += a.x * b.z; acc[0][3] += a.x * b.w;
            acc[1][0] += a.y * b.x; acc[1][1] += a.y * b.y; acc[1][2] += a.y * b.z; acc[1][3] += a.y * b.w;
            acc[2][0] += a.z * b.x; acc[2][1] += a.z * b.y; acc[2][2] += a.z * b.z; acc[2][3] += a.z * b.w;
            acc[3][0] += a.w * b.x; acc[3][1] += a.w * b.y; acc[3][2] += a.w * b.z; acc[3][3] += a.w * b.w;
        }
        __syncthreads();
    }
    const int col = col0 + tx * 4;
    const int cch = col >> 4;         // chunk
    const int coff = col & 15;        // offset in chunk
    #pragma unroll
    for (int i = 0; i < 4; ++i) {
        int gr = row0 + ty * 4 + i;
        if (gr < M) {
            ushort4 o;
            o.x = f2bf(acc[i][0]); o.y = f2bf(acc[i][1]);
            o.z = f2bf(acc[i][2]); o.w = f2bf(acc[i][3]);
            *(ushort4*)(C + ((size_t)cch * N + gr) * 16 + coff) = o;
        }
    }
}

// ---------------- k_prep: in-place scale hbT rows by isd[n] -----------------
__global__ __launch_bounds__(256) void k_prep(ushort* __restrict__ hT,
                                              const int* __restrict__ cnt,
                                              int N) {
    size_t base = ((size_t)blockIdx.x * 256 + threadIdx.x) * 8;  // elem idx
    if (base >= (size_t)N * 128) return;
    int n = (int)((base >> 4) % (size_t)N);     // base/16 = c*N + n
    float w = rsqrtf((float)(cnt[n] + 1));
    uint4 v = *(uint4*)(hT + base);
    uint4 o;
    o.x = (uint)f2bf(w * bf2f_lo(v.x)) | ((uint)f2bf(w * bf2f_hi(v.x)) << 16);
    o.y = (uint)f2bf(w * bf2f_lo(v.y)) | ((uint)f2bf(w * bf2f_hi(v.y)) << 16);
    o.z = (uint)f2bf(w * bf2f_lo(v.z)) | ((uint)f2bf(w * bf2f_hi(v.z)) << 16);
    o.w = (uint)f2bf(w * bf2f_lo(v.w)) | ((uint)f2bf(w * bf2f_hi(v.w)) << 16);
    *(uint4*)(hT + base) = o;
}

// ---------------- agg layer 1 (feature-split) -------------------------------
// Block: chunk c = blockIdx&7, nodes (blockIdx>>3)*4 + wave. Wave per
// (node, chunk): lane l -> edge l>>1 (+32 per t), feat-half f=l&1 (8 feats).
// hT rows are pre-scaled: out = isd_i*(sum_nbr scaled + scaled_self)+b, relu.
__global__ __launch_bounds__(256) void k_agg1(
        const ushort* __restrict__ hT,       // [8][N][16] scaled bf16
        const int* __restrict__ cnt,
        const ushort* __restrict__ slot,
        const float* __restrict__ bias,      // b1[128]
        const int* __restrict__ ovfcnt,
        const int2* __restrict__ ovf,
        ushort* __restrict__ h1T,            // [8][N][16] bf16 out
        int N) {
    const int c = blockIdx.x & 7;
    const int node = (blockIdx.x >> 3) * 4 + (threadIdx.x >> 6);
    const int lane = threadIdx.x & 63;
    if (node >= N) return;
    const int deg = cnt[node];
    const int degm = min(deg, CAP);
    const float isd_i = rsqrtf((float)(deg + 1));
    const int sl = (int)__builtin_nontemporal_load(slot + (size_t)node * CAP + lane);
    const int f = lane & 1;
    const ushort* hc = hT + (size_t)c * N * 16 + f * 8;
    const uint4 vself = *(const uint4*)(hc + (size_t)node * 16);  // early issue
    const int e0 = lane >> 1;

    float acc[8] = {};
    #pragma unroll
    for (int t = 0; t < 2; ++t) {
        int e = t * 32 + e0;
        int s = __shfl(sl, e);               // poison 0xAAAA=43690 < N: safe
        float vm = (e < degm) ? 1.f : 0.f;
        uint4 v = *(const uint4*)(hc + (size_t)s * 16);
        acc[0] = fmaf(vm, bf2f_lo(v.x), acc[0]);
        acc[1] = fmaf(vm, bf2f_hi(v.x), acc[1]);
        acc[2] = fmaf(vm, bf2f_lo(v.y), acc[2]);
        acc[3] = fmaf(vm, bf2f_hi(v.y), acc[3]);
        acc[4] = fmaf(vm, bf2f_lo(v.z), acc[4]);
        acc[5] = fmaf(vm, bf2f_hi(v.z), acc[5]);
        acc[6] = fmaf(vm, bf2f_lo(v.w), acc[6]);
        acc[7] = fmaf(vm, bf2f_hi(v.w), acc[7]);
    }
    #pragma unroll
    for (int k = 0; k < 8; ++k) {            // fold 32 same-f lanes
        acc[k] += __shfl_xor(acc[k], 2);
        acc[k] += __shfl_xor(acc[k], 4);
        acc[k] += __shfl_xor(acc[k], 8);
        acc[k] += __shfl_xor(acc[k], 16);
        acc[k] += __shfl_xor(acc[k], 32);
    }
    if (lane < 2) {
        int ovn = *ovfcnt;                   // ~always 0
        for (int q = 0; q < ovn; ++q) {
            int2 p = ovf[q];
            if (p.x == node) {
                uint4 v = *(const uint4*)(hc + (size_t)p.y * 16);
                acc[0] += bf2f_lo(v.x); acc[1] += bf2f_hi(v.x);
                acc[2] += bf2f_lo(v.y); acc[3] += bf2f_hi(v.y);
                acc[4] += bf2f_lo(v.z); acc[5] += bf2f_hi(v.z);
                acc[6] += bf2f_lo(v.w); acc[7] += bf2f_hi(v.w);
            }
        }
        const float* bp = bias + c * 16 + f * 8;
        float4 b0 = *(const float4*)bp;
        float4 b1v = *(const float4*)(bp + 4);
        float r0 = fmaxf((acc[0] + bf2f_lo(vself.x)) * isd_i + b0.x, 0.f);
        float r1 = fmaxf((acc[1] + bf2f_hi(vself.x)) * isd_i + b0.y, 0.f);
        float r2 = fmaxf((acc[2] + bf2f_lo(vself.y)) * isd_i + b0.z, 0.f);
        float r3 = fmaxf((acc[3] + bf2f_hi(vself.y)) * isd_i + b0.w, 0.f);
        float r4 = fmaxf((acc[4] + bf2f_lo(vself.z)) * isd_i + b1v.x, 0.f);
        float r5 = fmaxf((acc[5] + bf2f_hi(vself.z)) * isd_i + b1v.y, 0.f);
        float r6 = fmaxf((acc[6] + bf2f_lo(vself.w)) * isd_i + b1v.z, 0.f);
        float r7 = fmaxf((acc[7] + bf2f_hi(vself.w)) * isd_i + b1v.w, 0.f);
        uint4 o;
        o.x = (uint)f2bf(r0) | ((uint)f2bf(r1) << 16);
        o.y = (uint)f2bf(r2) | ((uint)f2bf(r3) << 16);
        o.z = (uint)f2bf(r4) | ((uint)f2bf(r5) << 16);
        o.w = (uint)f2bf(r6) | ((uint)f2bf(r7) << 16);
        *(uint4*)(h1T + ((size_t)c * N + node) * 16 + f * 8) = o;
    }
}

// ---------------- GEMM2: h2T[8][N][8] (bf16, isd-scaled) = h1T @ W2 ---------
__global__ __launch_bounds__(256) void k_gemm2(const ushort* __restrict__ Ah,  // h1T [8][N][16]
                                               const float* __restrict__ B,    // W2 128x64
                                               const int* __restrict__ cnt,
                                               ushort* __restrict__ C,         // h2T [8][N][8]
                                               int M) {
    __shared__ float At[32][68];
    __shared__ float Bs[32][64];
    const int tid = threadIdx.x;
    const int row0 = blockIdx.x * 64;
    const int tx = tid & 15;
    const int ty = tid >> 4;
    float acc[4][4] = {};

    for (int kb = 0; kb < 128; kb += 32) {
        #pragma unroll
        for (int t = 0; t < 2; ++t) {
            int f = tid * 4 + t * 1024;
            int r = f >> 5;
            int k = f & 31;
            int kk = kb + k;
            int cch = kk >> 4, j = kk & 15;
            uint2 v = make_uint2(0u, 0u);    // 4 bf16
            int gr = row0 + r;
            if (gr < M) v = *(const uint2*)(Ah + ((size_t)cch * M + gr) * 16 + j);
            At[k + 0][r] = bf2f_lo(v.x);
            At[k + 1][r] = bf2f_hi(v.x);
            At[k + 2][r] = bf2f_lo(v.y);
            At[k + 3][r] = bf2f_hi(v.y);
        }
        #pragma unroll
        for (int t = 0; t < 2; ++t) {
            int f = tid * 4 + t * 1024;
            int r = f >> 6;
            int cc = f & 63;
            *(float4*)&Bs[r][cc] = *(const float4*)(B + (size_t)(kb + r) * 64 + cc);
        }
        __syncthreads();
        #pragma unroll 8
        for (int k = 0; k < 32; ++k) {
            float4 a = *(const float4*)&At[k][ty * 4];
            float4 b = *(const float4*)&Bs[k][tx * 4];
            acc[0][0] += a.x * b.x; acc[0][1] += a.x * b.y; acc[0][2] += a.x * b.z; acc[0][3] += a.x * b.w;
            acc[1][0] += a.y * b.x; acc[1][1] += a.y * b.y; acc[1][2] += a.y * b.z; acc[1][3] += a.y * b.w;
            acc[2][0] += a.z * b.x; acc[2][1] += a.z * b.y; acc[2][2] += a.z * b.z; acc[2][3] += a.z * b.w;
            acc[3][0] += a.w * b.x; acc[3][1] += a.w * b.y; acc[3][2] += a.w * b.z; acc[3][3] += a.w * b.w;
        }
        __syncthreads();
    }
    const int col = tx * 4;
    const int cch = col >> 3;         // output chunk (8 feats)
    const int coff = col & 7;         // 0 or 4
    #pragma unroll
    for (int i = 0; i < 4; ++i) {
        int gr = row0 + ty * 4 + i;
        if (gr < M) {
            float w = rsqrtf((float)(cnt[gr] + 1));   // pre-scale by isd_src
            ushort4 o;
            o.x = f2bf(w * acc[i][0]); o.y = f2bf(w * acc[i][1]);
            o.z = f2bf(w * acc[i][2]); o.w = f2bf(w * acc[i][3]);
            *(ushort4*)(C + ((size_t)cch * M + gr) * 8 + coff) = o;
        }
    }
}

// ---------------- agg layer 2 (feature-split) -------------------------------
// Wave per (node, chunk): lane l -> edge l, one uint4 = full 16B row-chunk.
// h2T pre-scaled: out = isd_i*(sum_nbr scaled + scaled_self) + b2 (fp32 out).
__global__ __launch_bounds__(256) void k_agg2(
        const ushort* __restrict__ h2T,      // [8][N][8] scaled bf16
        const int* __restrict__ cnt,
        const ushort* __restrict__ slot,
        const float* __restrict__ bias,      // b2[64]
        const int* __restrict__ ovfcnt,
        const int2* __restrict__ ovf,
        float* __restrict__ out,             // N x 64 f32
        int N) {
    const int c = blockIdx.x & 7;
    const int node = (blockIdx.x >> 3) * 4 + (threadIdx.x >> 6);
    const int lane = threadIdx.x & 63;
    if (node >= N) return;
    const int deg = cnt[node];
    const int degm = min(deg, CAP);
    const float isd_i = rsqrtf((float)(deg + 1));
    const int sl = (int)__builtin_nontemporal_load(slot + (size_t)node * CAP + lane);
    const ushort* hc = h2T + (size_t)c * N * 8;
    const uint4 vself = *(const uint4*)(hc + (size_t)node * 8);

    float vm = (lane < degm) ? 1.f : 0.f;
    uint4 v = *(const uint4*)(hc + (size_t)sl * 8);   // poison idx < N: safe
    float acc[8];
    acc[0] = vm * bf2f_lo(v.x); acc[1] = vm * bf2f_hi(v.x);
    acc[2] = vm * bf2f_lo(v.y); acc[3] = vm * bf2f_hi(v.y);
    acc[4] = vm * bf2f_lo(v.z); acc[5] = vm * bf2f_hi(v.z);
    acc[6] = vm * bf2f_lo(v.w); acc[7] = vm * bf2f_hi(v.w);
    #pragma unroll
    for (int k = 0; k < 8; ++k) {
        acc[k] += __shfl_xor(acc[k], 1);
        acc[k] += __shfl_xor(acc[k], 2);
        acc[k] += __shfl_xor(acc[k], 4);
        acc[k] += __shfl_xor(acc[k], 8);
        acc[k] += __shfl_xor(acc[k], 16);
        acc[k] += __shfl_xor(acc[k], 32);
    }
    if (lane == 0) {
        int ovn = *ovfcnt;
        for (int q = 0; q < ovn; ++q) {
            int2 p = ovf[q];
            if (p.x == node) {
                uint4 vv = *(const uint4*)(hc + (size_t)p.y * 8);
                acc[0] += bf2f_lo(vv.x); acc[1] += bf2f_hi(vv.x);
                acc[2] += bf2f_lo(vv.y); acc[3] += bf2f_hi(vv.y);
                acc[4] += bf2f_lo(vv.z); acc[5] += bf2f_hi(vv.z);
                acc[6] += bf2f_lo(vv.w); acc[7] += bf2f_hi(vv.w);
            }
        }
        const float* bp = bias + c * 8;
        float4 b0 = *(const float4*)bp;
        float4 b1v = *(const float4*)(bp + 4);
        float4 r0, r1;
        r0.x = (acc[0] + bf2f_lo(vself.x)) * isd_i + b0.x;
        r0.y = (acc[1] + bf2f_hi(vself.x)) * isd_i + b0.y;
        r0.z = (acc[2] + bf2f_lo(vself.y)) * isd_i + b0.z;
        r0.w = (acc[3] + bf2f_hi(vself.y)) * isd_i + b0.w;
        r1.x = (acc[4] + bf2f_lo(vself.z)) * isd_i + b1v.x;
        r1.y = (acc[5] + bf2f_hi(vself.z)) * isd_i + b1v.y;
        r1.z = (acc[6] + bf2f_lo(vself.w)) * isd_i + b1v.z;
        r1.w = (acc[7] + bf2f_hi(vself.w)) * isd_i + b1v.w;
        float* op = out + (size_t)node * 64 + c * 8;
        *(float4*)op = r0;
        *(float4*)(op + 4) = r1;
    }
}

static inline size_t align256(size_t x) { return (x + 255) & ~(size_t)255; }

extern "C" void kernel_launch(void* const* d_in, const int* in_sizes, int n_in,
                              void* d_out, int out_size, void* d_ws, size_t ws_size,
                              hipStream_t stream) {
    const float* x  = (const float*)d_in[0];
    const int*   ei = (const int*)d_in[1];
    const float* W1 = (const float*)d_in[2];
    const float* b1 = (const float*)d_in[3];
    const float* W2 = (const float*)d_in[4];
    const float* b2 = (const float*)d_in[5];
    float* out = (float*)d_out;

    const int N = in_sizes[0] / GCN_IN;   // 50000
    const int E = in_sizes[1] / 2;        // 800000
    const int* src = ei;
    const int* dst = ei + E;

    char* ws = (char*)d_ws;
    size_t o = 0;
    int*    cnt    = (int*)(ws + o);     o += align256((size_t)N * 4);
    int*    ovfcnt = (int*)(ws + o);     o += 256;
    int2*   ovf    = (int2*)(ws + o);    o += align256((size_t)OVF_CAP * 8);
    ushort* slot   = (ushort*)(ws + o);  o += align256((size_t)N * CAP * 2);
    ushort* hbT    = (ushort*)(ws + o);  o += align256((size_t)N * GCN_H * 2);
    ushort* h1T    = (ushort*)(ws + o);  o += align256((size_t)N * GCN_H * 2);
    ushort* h2T    = (ushort*)(ws + o);  o += align256((size_t)N * GCN_OUT * 2);

    // zero cnt + ovfcnt (contiguous)
    hipMemsetAsync(cnt, 0, align256((size_t)N * 4) + 256, stream);

    // fused: XCD-partitioned scatter || GEMM1 -> hbT (chunked, unscaled)
    {
        int gemm_blocks = ((N + 63) / 64) * 2;
        k_fused1<<<SCAT_BLOCKS + gemm_blocks, 256, 0, stream>>>(
            src, dst, cnt, slot, ovfcnt, ovf, E, x, W1, hbT, N, N);
    }

    // in-place scale hbT rows by isd
    k_prep<<<(N * 16 + 255) / 256, 256, 0, stream>>>(hbT, cnt, N);

    // agg layer 1 (feature-split) -> h1T (chunked)
    k_agg1<<<8 * ((N + 3) / 4), 256, 0, stream>>>(hbT, cnt, slot, b1,
                                                  ovfcnt, ovf, h1T, N);

    // GEMM2: h1T @ W2 -> h2T (chunked, isd-scaled)
    k_gemm2<<<(N + 63) / 64, 256, 0, stream>>>(h1T, W2, cnt, h2T, N);

    // agg layer 2 (feature-split) -> out
    k_agg2<<<8 * ((N + 3) / 4), 256, 0, stream>>>(h2T, cnt, slot, b2,
                                                  ovfcnt, ovf, out, N);
}

// Round 7
// 218.915 us; speedup vs baseline: 2.4342x; 2.4342x over previous
//
#include <hip/hip_runtime.h>
#include <hip/hip_bf16.h>

// ---------------------------------------------------------------------------
// GCN 2-layer forward, round 7.
// Revert to round-5 agg structure (wave-per-node edge loop, wide gathers).
// Changes vs round 5:
//  - De-fused: standalone XCD-partitioned scatter (slot window stays
//    L2-resident without GEMM streams evicting it), then GEMM1.
//  - slot stored ushort (N<65536): halves scatter stores + slot reads.
//  - Rows pre-scaled by isd_src in GEMM epilogues (cnt is final pre-GEMM1
//    now) -> no per-edge weight gather in aggs, no k_prep.
//  - agg row masking via (e < degm) comparison, not shuffled weights.
// ---------------------------------------------------------------------------

#define GCN_IN   128
#define GCN_H    128
#define GCN_OUT  64
#define CAP      64
#define OVF_CAP  65536
#define SCAT_BLOCKS 1024   // 8 partitions x 128 blocks

__device__ __forceinline__ ushort f2bf(float f) {     // fp32 -> bf16 RNE
    uint b = __float_as_uint(f);
    b = (b + 0x7FFFu + ((b >> 16) & 1u)) >> 16;
    return (ushort)b;
}
__device__ __forceinline__ float bf2f_lo(uint u) { return __uint_as_float(u << 16); }
__device__ __forceinline__ float bf2f_hi(uint u) { return __uint_as_float(u & 0xFFFF0000u); }

// ---------------- standalone XCD-partitioned scatter ------------------------
__global__ __launch_bounds__(256) void k_scatter(
        const int* __restrict__ src, const int* __restrict__ dst,
        int* __restrict__ cnt, ushort* __restrict__ slot,
        int* __restrict__ ovfcnt, int2* __restrict__ ovf, int E, int N) {
    const int part = blockIdx.x & 7;           // round-robin -> XCD part
    const int psz  = (N + 7) >> 3;
    const int lo   = part * psz;
    const int hi   = min(lo + psz, N);
    const int bip  = blockIdx.x >> 3;          // 0..127 within partition
    const int stride = (SCAT_BLOCKS >> 3) * 256;
    for (int e = bip * 256 + threadIdx.x; e < E; e += stride) {
        int d = __builtin_nontemporal_load(dst + e);
        int s = __builtin_nontemporal_load(src + e);
        if (d >= lo && d < hi) {
            int pos = atomicAdd(&cnt[d], 1);
            if (pos < CAP) {
                slot[(size_t)d * CAP + pos] = (ushort)s;  // L2-resident window
            } else {
                int q = atomicAdd(ovfcnt, 1);
                if (q < OVF_CAP) ovf[q] = make_int2(d, s);
            }
        }
    }
}

// ---------------- GEMM1: hb[N][128] bf16 (isd-scaled) = x @ W1 --------------
__global__ __launch_bounds__(256) void k_gemm1(const float* __restrict__ A,
                                               const float* __restrict__ B,
                                               const int* __restrict__ cnt,
                                               ushort* __restrict__ C, int M) {
    __shared__ float At[32][68];   // At[k][m], pad 68 -> conflict-free b128
    __shared__ float Bs[32][64];
    const int tid = threadIdx.x;
    const int row0 = blockIdx.x * 64;
    const int col0 = blockIdx.y * 64;
    const int tx = tid & 15;
    const int ty = tid >> 4;
    float acc[4][4] = {};

    for (int kb = 0; kb < 128; kb += 32) {
        #pragma unroll
        for (int t = 0; t < 2; ++t) {
            int f = tid * 4 + t * 1024;
            int r = f >> 5;
            int k = f & 31;
            float4 v = make_float4(0.f, 0.f, 0.f, 0.f);
            int gr = row0 + r;
            if (gr < M) v = *(const float4*)(A + (size_t)gr * 128 + kb + k);
            At[k + 0][r] = v.x;
            At[k + 1][r] = v.y;
            At[k + 2][r] = v.z;
            At[k + 3][r] = v.w;
        }
        #pragma unroll
        for (int t = 0; t < 2; ++t) {
            int f = tid * 4 + t * 1024;
            int r = f >> 6;
            int c = f & 63;
            *(float4*)&Bs[r][c] = *(const float4*)(B + (size_t)(kb + r) * 128 + col0 + c);
        }
        __syncthreads();
        #pragma unroll 8
        for (int k = 0; k < 32; ++k) {
            float4 a = *(const float4*)&At[k][ty * 4];
            float4 b = *(const float4*)&Bs[k][tx * 4];
            acc[0][0] += a.x * b.x; acc[0][1] += a.x * b.y; acc[0][2] += a.x * b.z; acc[0][3] += a.x * b.w;
            acc[1][0] += a.y * b.x; acc[1][1] += a.y * b.y; acc[1][2] += a.y * b.z; acc[1][3] += a.y * b.w;
            acc[2][0] += a.z * b.x; acc[2][1] += a.z * b.y; acc[2][2] += a.z * b.z; acc[2][3] += a.z * b.w;
            acc[3][0] += a.w * b.x; acc[3][1] += a.w * b.y; acc[3][2] += a.w * b.z; acc[3][3] += a.w * b.w;
        }
        __syncthreads();
    }
    #pragma unroll
    for (int i = 0; i < 4; ++i) {
        int gr = row0 + ty * 4 + i;
        if (gr < M) {
            float w = rsqrtf((float)(cnt[gr] + 1));   // pre-scale by isd_src
            ushort4 o;
            o.x = f2bf(w * acc[i][0]); o.y = f2bf(w * acc[i][1]);
            o.z = f2bf(w * acc[i][2]); o.w = f2bf(w * acc[i][3]);
            *(ushort4*)(C + (size_t)gr * 128 + col0 + tx * 4) = o;
        }
    }
}

// ---------------- GEMM2: h2[N][64] bf16 (isd-scaled) = h1 @ W2 --------------
__global__ __launch_bounds__(256) void k_gemm2(const ushort* __restrict__ A,
                                               const float* __restrict__ B,
                                               const int* __restrict__ cnt,
                                               ushort* __restrict__ C, int M) {
    __shared__ float At[32][68];
    __shared__ float Bs[32][64];
    const int tid = threadIdx.x;
    const int row0 = blockIdx.x * 64;
    const int tx = tid & 15;
    const int ty = tid >> 4;
    float acc[4][4] = {};

    for (int kb = 0; kb < 128; kb += 32) {
        #pragma unroll
        for (int t = 0; t < 2; ++t) {
            int f = tid * 4 + t * 1024;
            int r = f >> 5;
            int k = f & 31;
            uint2 v = make_uint2(0u, 0u);    // 4 bf16
            int gr = row0 + r;
            if (gr < M) v = *(const uint2*)(A + (size_t)gr * 128 + kb + k);
            At[k + 0][r] = bf2f_lo(v.x);
            At[k + 1][r] = bf2f_hi(v.x);
            At[k + 2][r] = bf2f_lo(v.y);
            At[k + 3][r] = bf2f_hi(v.y);
        }
        #pragma unroll
        for (int t = 0; t < 2; ++t) {
            int f = tid * 4 + t * 1024;
            int r = f >> 6;
            int c = f & 63;
            *(float4*)&Bs[r][c] = *(const float4*)(B + (size_t)(kb + r) * 64 + c);
        }
        __syncthreads();
        #pragma unroll 8
        for (int k = 0; k < 32; ++k) {
            float4 a = *(const float4*)&At[k][ty * 4];
            float4 b = *(const float4*)&Bs[k][tx * 4];
            acc[0][0] += a.x * b.x; acc[0][1] += a.x * b.y; acc[0][2] += a.x * b.z; acc[0][3] += a.x * b.w;
            acc[1][0] += a.y * b.x; acc[1][1] += a.y * b.y; acc[1][2] += a.y * b.z; acc[1][3] += a.y * b.w;
            acc[2][0] += a.z * b.x; acc[2][1] += a.z * b.y; acc[2][2] += a.z * b.z; acc[2][3] += a.z * b.w;
            acc[3][0] += a.w * b.x; acc[3][1] += a.w * b.y; acc[3][2] += a.w * b.z; acc[3][3] += a.w * b.w;
        }
        __syncthreads();
    }
    #pragma unroll
    for (int i = 0; i < 4; ++i) {
        int gr = row0 + ty * 4 + i;
        if (gr < M) {
            float w = rsqrtf((float)(cnt[gr] + 1));   // pre-scale by isd_src
            ushort4 o;
            o.x = f2bf(w * acc[i][0]); o.y = f2bf(w * acc[i][1]);
            o.z = f2bf(w * acc[i][2]); o.w = f2bf(w * acc[i][3]);
            *(ushort4*)(C + (size_t)gr * 64 + tx * 4) = o;
        }
    }
}

// ---------------- agg layer 1: F=128, scaled bf16 in, bf16 out, relu --------
// One wave per node. Quad q=lane>>4 handles edge j+q / j+4+q; lane holds
// features 8i..8i+7 (i=lane&15): one uint4 gather = 4 rows (1KB). Rows are
// pre-scaled: h1 = relu(isd_i*(sum_nbr scaled + scaled_self) + b1).
__global__ __launch_bounds__(256) void k_agg128(const ushort* __restrict__ h,
                                                const int* __restrict__ cnt,
                                                const ushort* __restrict__ slot,
                                                const float* __restrict__ bias,
                                                const int* __restrict__ ovfcnt,
                                                const int2* __restrict__ ovf,
                                                ushort* __restrict__ out, int n) {
    int node = (blockIdx.x * 256 + threadIdx.x) >> 6;
    int lane = threadIdx.x & 63;
    if (node >= n) return;
    int deg = cnt[node];
    int degm = min(deg, CAP);
    float isd_i = rsqrtf((float)(deg + 1));
    int sidx = (int)__builtin_nontemporal_load(slot + (size_t)node * CAP + lane);

    const int q = lane >> 4;          // 0..3
    const int i = lane & 15;          // 0..15
    const ushort* hp = h + 8 * i;     // feature offset (8 bf16 per lane)

    float acc[8] = {};
    for (int j = 0; j < degm; j += 8) {          // 8 edges per iter, 2 gathers
        int j0 = j + q;
        int j1 = j + 4 + q;
        int   s0 = __shfl(sidx, j0);             // garbage idx < 65536: safe
        int   s1 = __shfl(sidx, j1);
        float w0 = (j0 < degm) ? 1.f : 0.f;
        float w1 = (j1 < degm) ? 1.f : 0.f;
        uint4 v0 = *(const uint4*)(hp + (size_t)s0 * 128);
        uint4 v1 = *(const uint4*)(hp + (size_t)s1 * 128);
        acc[0] += w0 * bf2f_lo(v0.x) + w1 * bf2f_lo(v1.x);
        acc[1] += w0 * bf2f_hi(v0.x) + w1 * bf2f_hi(v1.x);
        acc[2] += w0 * bf2f_lo(v0.y) + w1 * bf2f_lo(v1.y);
        acc[3] += w0 * bf2f_hi(v0.y) + w1 * bf2f_hi(v1.y);
        acc[4] += w0 * bf2f_lo(v0.z) + w1 * bf2f_lo(v1.z);
        acc[5] += w0 * bf2f_hi(v0.z) + w1 * bf2f_hi(v1.z);
        acc[6] += w0 * bf2f_lo(v0.w) + w1 * bf2f_lo(v1.w);
        acc[7] += w0 * bf2f_hi(v0.w) + w1 * bf2f_hi(v1.w);
    }
    int ovn = *ovfcnt;                            // ~always 0
    for (int t = 0; t < ovn; ++t) {
        int2 p = ovf[t];
        if (p.x == node && q == 0) {
            uint4 v0 = *(const uint4*)(hp + (size_t)p.y * 128);
            acc[0] += bf2f_lo(v0.x); acc[1] += bf2f_hi(v0.x);
            acc[2] += bf2f_lo(v0.y); acc[3] += bf2f_hi(v0.y);
            acc[4] += bf2f_lo(v0.z); acc[5] += bf2f_hi(v0.z);
            acc[6] += bf2f_lo(v0.w); acc[7] += bf2f_hi(v0.w);
        }
    }
    #pragma unroll
    for (int k = 0; k < 8; ++k) {                 // fold quads
        acc[k] += __shfl_xor(acc[k], 16);
        acc[k] += __shfl_xor(acc[k], 32);
    }
    if (q == 0) {
        uint4 vs = *(const uint4*)(hp + (size_t)node * 128);  // scaled self
        float4 ba = *(const float4*)(bias + 8 * i);
        float4 bb = *(const float4*)(bias + 8 * i + 4);
        float r0 = fmaxf((acc[0] + bf2f_lo(vs.x)) * isd_i + ba.x, 0.f);
        float r1 = fmaxf((acc[1] + bf2f_hi(vs.x)) * isd_i + ba.y, 0.f);
        float r2 = fmaxf((acc[2] + bf2f_lo(vs.y)) * isd_i + ba.z, 0.f);
        float r3 = fmaxf((acc[3] + bf2f_hi(vs.y)) * isd_i + ba.w, 0.f);
        float r4 = fmaxf((acc[4] + bf2f_lo(vs.z)) * isd_i + bb.x, 0.f);
        float r5 = fmaxf((acc[5] + bf2f_hi(vs.z)) * isd_i + bb.y, 0.f);
        float r6 = fmaxf((acc[6] + bf2f_lo(vs.w)) * isd_i + bb.z, 0.f);
        float r7 = fmaxf((acc[7] + bf2f_hi(vs.w)) * isd_i + bb.w, 0.f);
        uint4 o;
        o.x = (uint)f2bf(r0) | ((uint)f2bf(r1) << 16);
        o.y = (uint)f2bf(r2) | ((uint)f2bf(r3) << 16);
        o.z = (uint)f2bf(r4) | ((uint)f2bf(r5) << 16);
        o.w = (uint)f2bf(r6) | ((uint)f2bf(r7) << 16);
        *(uint4*)(out + (size_t)node * 128 + 8 * i) = o;
    }
}

// ---------------- agg layer 2: F=64, scaled bf16 in, fp32 out ---------------
// Oct g=lane>>3 handles edge j+g / j+8+g; lane holds features 8i..8i+7
// (i=lane&7): one uint4 gather = 8 rows (1KB).
__global__ __launch_bounds__(256) void k_agg64(const ushort* __restrict__ h,
                                               const int* __restrict__ cnt,
                                               const ushort* __restrict__ slot,
                                               const float* __restrict__ bias,
                                               const int* __restrict__ ovfcnt,
                                               const int2* __restrict__ ovf,
                                               float* __restrict__ out, int n) {
    int node = (blockIdx.x * 256 + threadIdx.x) >> 6;
    int lane = threadIdx.x & 63;
    if (node >= n) return;
    int deg = cnt[node];
    int degm = min(deg, CAP);
    float isd_i = rsqrtf((float)(deg + 1));
    int sidx = (int)__builtin_nontemporal_load(slot + (size_t)node * CAP + lane);

    const int g = lane >> 3;          // 0..7
    const int i = lane & 7;           // 0..7
    const ushort* hp = h + 8 * i;

    float acc[8] = {};
    for (int j = 0; j < degm; j += 16) {         // 16 edges per iter, 2 gathers
        int j0 = j + g;
        int j1 = j + 8 + g;
        int   s0 = __shfl(sidx, j0);
        int   s1 = __shfl(sidx, j1);
        float w0 = (j0 < degm) ? 1.f : 0.f;
        float w1 = (j1 < degm) ? 1.f : 0.f;
        uint4 v0 = *(const uint4*)(hp + (size_t)s0 * 64);
        uint4 v1 = *(const uint4*)(hp + (size_t)s1 * 64);
        acc[0] += w0 * bf2f_lo(v0.x) + w1 * bf2f_lo(v1.x);
        acc[1] += w0 * bf2f_hi(v0.x) + w1 * bf2f_hi(v1.x);
        acc[2] += w0 * bf2f_lo(v0.y) + w1 * bf2f_lo(v1.y);
        acc[3] += w0 * bf2f_hi(v0.y) + w1 * bf2f_hi(v1.y);
        acc[4] += w0 * bf2f_lo(v0.z) + w1 * bf2f_lo(v1.z);
        acc[5] += w0 * bf2f_hi(v0.z) + w1 * bf2f_hi(v1.z);
        acc[6] += w0 * bf2f_lo(v0.w) + w1 * bf2f_lo(v1.w);
        acc[7] += w0 * bf2f_hi(v0.w) + w1 * bf2f_hi(v1.w);
    }
    int ovn = *ovfcnt;
    for (int t = 0; t < ovn; ++t) {
        int2 p = ovf[t];
        if (p.x == node && g == 0) {
            uint4 v0 = *(const uint4*)(hp + (size_t)p.y * 64);
            acc[0] += bf2f_lo(v0.x); acc[1] += bf2f_hi(v0.x);
            acc[2] += bf2f_lo(v0.y); acc[3] += bf2f_hi(v0.y);
            acc[4] += bf2f_lo(v0.z); acc[5] += bf2f_hi(v0.z);
            acc[6] += bf2f_lo(v0.w); acc[7] += bf2f_hi(v0.w);
        }
    }
    #pragma unroll
    for (int k = 0; k < 8; ++k) {                // fold octs
        acc[k] += __shfl_xor(acc[k], 8);
        acc[k] += __shfl_xor(acc[k], 16);
        acc[k] += __shfl_xor(acc[k], 32);
    }
    if (g == 0) {
        uint4 vs = *(const uint4*)(hp + (size_t)node * 64);   // scaled self
        float4 ba = *(const float4*)(bias + 8 * i);
        float4 bb = *(const float4*)(bias + 8 * i + 4);
        float4 r0, r1;
        r0.x = (acc[0] + bf2f_lo(vs.x)) * isd_i + ba.x;
        r0.y = (acc[1] + bf2f_hi(vs.x)) * isd_i + ba.y;
        r0.z = (acc[2] + bf2f_lo(vs.y)) * isd_i + ba.z;
        r0.w = (acc[3] + bf2f_hi(vs.y)) * isd_i + ba.w;
        r1.x = (acc[4] + bf2f_lo(vs.z)) * isd_i + bb.x;
        r1.y = (acc[5] + bf2f_hi(vs.z)) * isd_i + bb.y;
        r1.z = (acc[6] + bf2f_lo(vs.w)) * isd_i + bb.z;
        r1.w = (acc[7] + bf2f_hi(vs.w)) * isd_i + bb.w;
        float* op = out + (size_t)node * 64 + 8 * i;
        *(float4*)op = r0;
        *(float4*)(op + 4) = r1;
    }
}

static inline size_t align256(size_t x) { return (x + 255) & ~(size_t)255; }

extern "C" void kernel_launch(void* const* d_in, const int* in_sizes, int n_in,
                              void* d_out, int out_size, void* d_ws, size_t ws_size,
                              hipStream_t stream) {
    const float* x  = (const float*)d_in[0];
    const int*   ei = (const int*)d_in[1];
    const float* W1 = (const float*)d_in[2];
    const float* b1 = (const float*)d_in[3];
    const float* W2 = (const float*)d_in[4];
    const float* b2 = (const float*)d_in[5];
    float* out = (float*)d_out;

    const int N = in_sizes[0] / GCN_IN;   // 50000
    const int E = in_sizes[1] / 2;        // 800000
    const int* src = ei;
    const int* dst = ei + E;

    char* ws = (char*)d_ws;
    size_t o = 0;
    int*    cnt    = (int*)(ws + o);     o += align256((size_t)N * 4);
    int*    ovfcnt = (int*)(ws + o);     o += 256;
    int2*   ovf    = (int2*)(ws + o);    o += align256((size_t)OVF_CAP * 8);
    ushort* slot   = (ushort*)(ws + o);  o += align256((size_t)N * CAP * 2);
    ushort* hb     = (ushort*)(ws + o);  o += align256((size_t)N * GCN_H * 2);
    ushort* h1b    = (ushort*)(ws + o);  o += align256((size_t)N * GCN_H * 2);
    ushort* h2b    = (ushort*)(ws + o);  o += align256((size_t)N * GCN_OUT * 2);

    // zero cnt + ovfcnt (contiguous)
    hipMemsetAsync(cnt, 0, align256((size_t)N * 4) + 256, stream);

    // 1. standalone XCD-partitioned scatter (slot window L2-resident)
    k_scatter<<<SCAT_BLOCKS, 256, 0, stream>>>(src, dst, cnt, slot,
                                               ovfcnt, ovf, E, N);

    // 2. GEMM1: x @ W1 -> hb (bf16, isd-scaled epilogue)
    {
        dim3 g((N + 63) / 64, 2);
        k_gemm1<<<g, 256, 0, stream>>>(x, W1, cnt, hb, N);
    }

    // 3. agg layer 1 -> h1b (bf16, plain)
    k_agg128<<<(N * 64 + 255) / 256, 256, 0, stream>>>(hb, cnt, slot, b1,
                                                       ovfcnt, ovf, h1b, N);
    // 4. GEMM2: h1b @ W2 -> h2b (bf16, isd-scaled epilogue)
    k_gemm2<<<(N + 63) / 64, 256, 0, stream>>>(h1b, W2, cnt, h2b, N);

    // 5. agg layer 2 -> out (fp32)
    k_agg64<<<(N * 64 + 255) / 256, 256, 0, stream>>>(h2b, cnt, slot, b2,
                                                      ovfcnt, ovf, out, N);
}

// Round 8
// 205.602 us; speedup vs baseline: 2.5918x; 1.0648x over previous
//
#include <hip/hip_runtime.h>
#include <hip/hip_bf16.h>

// ---------------------------------------------------------------------------
// GCN 2-layer forward, round 8.
// Changes vs round 7:
//  - GEMM1/GEMM2 ported to MFMA (v_mfma_f32_16x16x32_bf16). A-frag
//    A[m=lane&15][k=quad*8+j], B-frag B[n=lane&15][k=quad*8+j], C/D
//    row=quad*4+reg, col=lane&15 (m89/m91-verified layouts). LDS tiles
//    padded to 136 shorts/row (272B, 16B-aligned, 2-way conflicts = free).
//    gemm2's A (h1b) is already bf16 -> staging is a plain copy.
//  - Scatter: 2048 blocks (13 serial iters/thread, was 24) -- same
//    XCD-partitioned L2-resident windows.
//  - Aggs unchanged from round 7 (wave-per-node, wide uint4 gathers,
//    prescaled rows).
// Known fixed cost: harness re-poison of d_ws (~268MB fill = ~50us) sits
// inside the timed window; kernel budget is dur_us - ~52.
// ---------------------------------------------------------------------------

#define GCN_IN   128
#define GCN_H    128
#define GCN_OUT  64
#define CAP      64
#define OVF_CAP  65536
#define SCAT_BLOCKS 2048   // 8 partitions x 256 blocks

using short8 = __attribute__((ext_vector_type(8))) short;   // 8 bf16, 4 VGPRs
using f32x4  = __attribute__((ext_vector_type(4))) float;   // MFMA acc

__device__ __forceinline__ ushort f2bf(float f) {     // fp32 -> bf16 RNE
    uint b = __float_as_uint(f);
    b = (b + 0x7FFFu + ((b >> 16) & 1u)) >> 16;
    return (ushort)b;
}
__device__ __forceinline__ float bf2f_lo(uint u) { return __uint_as_float(u << 16); }
__device__ __forceinline__ float bf2f_hi(uint u) { return __uint_as_float(u & 0xFFFF0000u); }

// ---------------- XCD-partitioned scatter -----------------------------------
__global__ __launch_bounds__(256) void k_scatter(
        const int* __restrict__ src, const int* __restrict__ dst,
        int* __restrict__ cnt, ushort* __restrict__ slot,
        int* __restrict__ ovfcnt, int2* __restrict__ ovf, int E, int N) {
    const int part = blockIdx.x & 7;           // round-robin -> XCD part
    const int psz  = (N + 7) >> 3;
    const int lo   = part * psz;
    const int hi   = min(lo + psz, N);
    const int bip  = blockIdx.x >> 3;          // 0..255 within partition
    const int stride = (SCAT_BLOCKS >> 3) * 256;
    for (int e = bip * 256 + threadIdx.x; e < E; e += stride) {
        int d = __builtin_nontemporal_load(dst + e);
        int s = __builtin_nontemporal_load(src + e);
        if (d >= lo && d < hi) {
            int pos = atomicAdd(&cnt[d], 1);
            if (pos < CAP) {
                slot[(size_t)d * CAP + pos] = (ushort)s;  // L2-resident window
            } else {
                int q = atomicAdd(ovfcnt, 1);
                if (q < OVF_CAP) ovf[q] = make_int2(d, s);
            }
        }
    }
}

// ---------------- MFMA GEMM1: hb[N][128] bf16 (isd-scaled) = x @ W1 ---------
// Block = 64 rows x 128 cols, 4 waves; wave w: rows [16w,16w+16) x 8 n-tiles.
__global__ __launch_bounds__(256) void k_gemm1(const float* __restrict__ A,
                                               const float* __restrict__ B,
                                               const int* __restrict__ cnt,
                                               ushort* __restrict__ C, int M) {
    __shared__ __align__(16) ushort As[64][136];    // [m][k] bf16, pad->272B
    __shared__ __align__(16) ushort Bs[128][136];   // [n][k] bf16 (W1^T)
    const int tid  = threadIdx.x;
    const int w    = tid >> 6;
    const int lane = tid & 63;
    const int l15  = lane & 15;
    const int q8   = (lane >> 4) * 8;
    const int row0 = blockIdx.x * 64;

    // stage A: 64 rows x 128 k fp32 -> bf16
    #pragma unroll
    for (int t = 0; t < 8; ++t) {
        int f = tid * 4 + t * 1024;
        int r = f >> 7;
        int k = f & 127;
        float4 v = make_float4(0.f, 0.f, 0.f, 0.f);
        int gr = row0 + r;
        if (gr < M) v = *(const float4*)(A + (size_t)gr * 128 + k);
        ushort4 o;
        o.x = f2bf(v.x); o.y = f2bf(v.y); o.z = f2bf(v.z); o.w = f2bf(v.w);
        *(ushort4*)&As[r][k] = o;
    }
    // stage B: W1[k][n] fp32 -> Bs[n][k] bf16 (transpose)
    #pragma unroll
    for (int t = 0; t < 16; ++t) {
        int f = tid * 4 + t * 1024;
        int k = f >> 7;
        int n = f & 127;
        float4 v = *(const float4*)(B + (size_t)k * 128 + n);
        Bs[n + 0][k] = f2bf(v.x);
        Bs[n + 1][k] = f2bf(v.y);
        Bs[n + 2][k] = f2bf(v.z);
        Bs[n + 3][k] = f2bf(v.w);
    }
    __syncthreads();

    f32x4 acc[8];
    #pragma unroll
    for (int t = 0; t < 8; ++t) {
        acc[t][0] = 0.f; acc[t][1] = 0.f; acc[t][2] = 0.f; acc[t][3] = 0.f;
    }
    #pragma unroll
    for (int kt = 0; kt < 4; ++kt) {
        short8 a = *(const short8*)&As[16 * w + l15][32 * kt + q8];
        #pragma unroll
        for (int t = 0; t < 8; ++t) {
            short8 b = *(const short8*)&Bs[16 * t + l15][32 * kt + q8];
            acc[t] = __builtin_amdgcn_mfma_f32_16x16x32_bf16(a, b, acc[t], 0, 0, 0);
        }
    }
    // epilogue: C[row][col], row=16w+quad*4+reg, col=16t+l15; scale by isd_row
    const int quad = lane >> 4;
    #pragma unroll
    for (int r = 0; r < 4; ++r) {
        int grow = row0 + 16 * w + quad * 4 + r;
        if (grow < M) {
            float ws = rsqrtf((float)(cnt[grow] + 1));
            #pragma unroll
            for (int t = 0; t < 8; ++t) {
                C[(size_t)grow * 128 + 16 * t + l15] = f2bf(ws * acc[t][r]);
            }
        }
    }
}

// ---------------- MFMA GEMM2: h2[N][64] bf16 (isd-scaled) = h1 @ W2 ---------
__global__ __launch_bounds__(256) void k_gemm2(const ushort* __restrict__ A,
                                               const float* __restrict__ B,
                                               const int* __restrict__ cnt,
                                               ushort* __restrict__ C, int M) {
    __shared__ __align__(16) ushort As[64][136];   // [m][k] bf16
    __shared__ __align__(16) ushort Bs[64][136];   // [n][k] bf16 (W2^T)
    const int tid  = threadIdx.x;
    const int w    = tid >> 6;
    const int lane = tid & 63;
    const int l15  = lane & 15;
    const int q8   = (lane >> 4) * 8;
    const int row0 = blockIdx.x * 64;

    // stage A: 64 rows x 128 k bf16 (plain copy)
    #pragma unroll
    for (int t = 0; t < 4; ++t) {
        int f = tid * 8 + t * 2048;
        int r = f >> 7;
        int k = f & 127;
        uint4 v = make_uint4(0u, 0u, 0u, 0u);
        int gr = row0 + r;
        if (gr < M) v = *(const uint4*)(A + (size_t)gr * 128 + k);
        *(uint4*)&As[r][k] = v;
    }
    // stage B: W2[k][n] fp32 -> Bs[n][k] bf16 (transpose)
    #pragma unroll
    for (int t = 0; t < 8; ++t) {
        int f = tid * 4 + t * 1024;
        int k = f >> 6;
        int n = f & 63;
        float4 v = *(const float4*)(B + (size_t)k * 64 + n);
        Bs[n + 0][k] = f2bf(v.x);
        Bs[n + 1][k] = f2bf(v.y);
        Bs[n + 2][k] = f2bf(v.z);
        Bs[n + 3][k] = f2bf(v.w);
    }
    __syncthreads();

    f32x4 acc[4];
    #pragma unroll
    for (int t = 0; t < 4; ++t) {
        acc[t][0] = 0.f; acc[t][1] = 0.f; acc[t][2] = 0.f; acc[t][3] = 0.f;
    }
    #pragma unroll
    for (int kt = 0; kt < 4; ++kt) {
        short8 a = *(const short8*)&As[16 * w + l15][32 * kt + q8];
        #pragma unroll
        for (int t = 0; t < 4; ++t) {
            short8 b = *(const short8*)&Bs[16 * t + l15][32 * kt + q8];
            acc[t] = __builtin_amdgcn_mfma_f32_16x16x32_bf16(a, b, acc[t], 0, 0, 0);
        }
    }
    const int quad = lane >> 4;
    #pragma unroll
    for (int r = 0; r < 4; ++r) {
        int grow = row0 + 16 * w + quad * 4 + r;
        if (grow < M) {
            float ws = rsqrtf((float)(cnt[grow] + 1));
            #pragma unroll
            for (int t = 0; t < 4; ++t) {
                C[(size_t)grow * 64 + 16 * t + l15] = f2bf(ws * acc[t][r]);
            }
        }
    }
}

// ---------------- agg layer 1: F=128, scaled bf16 in, bf16 out, relu --------
__global__ __launch_bounds__(256) void k_agg128(const ushort* __restrict__ h,
                                                const int* __restrict__ cnt,
                                                const ushort* __restrict__ slot,
                                                const float* __restrict__ bias,
                                                const int* __restrict__ ovfcnt,
                                                const int2* __restrict__ ovf,
                                                ushort* __restrict__ out, int n) {
    int node = (blockIdx.x * 256 + threadIdx.x) >> 6;
    int lane = threadIdx.x & 63;
    if (node >= n) return;
    int deg = cnt[node];
    int degm = min(deg, CAP);
    float isd_i = rsqrtf((float)(deg + 1));
    int sidx = (int)__builtin_nontemporal_load(slot + (size_t)node * CAP + lane);

    const int q = lane >> 4;          // 0..3
    const int i = lane & 15;          // 0..15
    const ushort* hp = h + 8 * i;     // feature offset (8 bf16 per lane)

    float acc[8] = {};
    for (int j = 0; j < degm; j += 8) {          // 8 edges per iter, 2 gathers
        int j0 = j + q;
        int j1 = j + 4 + q;
        int   s0 = __shfl(sidx, j0);
        int   s1 = __shfl(sidx, j1);
        float w0 = (j0 < degm) ? 1.f : 0.f;
        float w1 = (j1 < degm) ? 1.f : 0.f;
        uint4 v0 = *(const uint4*)(hp + (size_t)s0 * 128);
        uint4 v1 = *(const uint4*)(hp + (size_t)s1 * 128);
        acc[0] += w0 * bf2f_lo(v0.x) + w1 * bf2f_lo(v1.x);
        acc[1] += w0 * bf2f_hi(v0.x) + w1 * bf2f_hi(v1.x);
        acc[2] += w0 * bf2f_lo(v0.y) + w1 * bf2f_lo(v1.y);
        acc[3] += w0 * bf2f_hi(v0.y) + w1 * bf2f_hi(v1.y);
        acc[4] += w0 * bf2f_lo(v0.z) + w1 * bf2f_lo(v1.z);
        acc[5] += w0 * bf2f_hi(v0.z) + w1 * bf2f_hi(v1.z);
        acc[6] += w0 * bf2f_lo(v0.w) + w1 * bf2f_lo(v1.w);
        acc[7] += w0 * bf2f_hi(v0.w) + w1 * bf2f_hi(v1.w);
    }
    int ovn = *ovfcnt;                            // ~always 0
    for (int t = 0; t < ovn; ++t) {
        int2 p = ovf[t];
        if (p.x == node && q == 0) {
            uint4 v0 = *(const uint4*)(hp + (size_t)p.y * 128);
            acc[0] += bf2f_lo(v0.x); acc[1] += bf2f_hi(v0.x);
            acc[2] += bf2f_lo(v0.y); acc[3] += bf2f_hi(v0.y);
            acc[4] += bf2f_lo(v0.z); acc[5] += bf2f_hi(v0.z);
            acc[6] += bf2f_lo(v0.w); acc[7] += bf2f_hi(v0.w);
        }
    }
    #pragma unroll
    for (int k = 0; k < 8; ++k) {                 // fold quads
        acc[k] += __shfl_xor(acc[k], 16);
        acc[k] += __shfl_xor(acc[k], 32);
    }
    if (q == 0) {
        uint4 vs = *(const uint4*)(hp + (size_t)node * 128);  // scaled self
        float4 ba = *(const float4*)(bias + 8 * i);
        float4 bb = *(const float4*)(bias + 8 * i + 4);
        float r0 = fmaxf((acc[0] + bf2f_lo(vs.x)) * isd_i + ba.x, 0.f);
        float r1 = fmaxf((acc[1] + bf2f_hi(vs.x)) * isd_i + ba.y, 0.f);
        float r2 = fmaxf((acc[2] + bf2f_lo(vs.y)) * isd_i + ba.z, 0.f);
        float r3 = fmaxf((acc[3] + bf2f_hi(vs.y)) * isd_i + ba.w, 0.f);
        float r4 = fmaxf((acc[4] + bf2f_lo(vs.z)) * isd_i + bb.x, 0.f);
        float r5 = fmaxf((acc[5] + bf2f_hi(vs.z)) * isd_i + bb.y, 0.f);
        float r6 = fmaxf((acc[6] + bf2f_lo(vs.w)) * isd_i + bb.z, 0.f);
        float r7 = fmaxf((acc[7] + bf2f_hi(vs.w)) * isd_i + bb.w, 0.f);
        uint4 o;
        o.x = (uint)f2bf(r0) | ((uint)f2bf(r1) << 16);
        o.y = (uint)f2bf(r2) | ((uint)f2bf(r3) << 16);
        o.z = (uint)f2bf(r4) | ((uint)f2bf(r5) << 16);
        o.w = (uint)f2bf(r6) | ((uint)f2bf(r7) << 16);
        *(uint4*)(out + (size_t)node * 128 + 8 * i) = o;
    }
}

// ---------------- agg layer 2: F=64, scaled bf16 in, fp32 out ---------------
__global__ __launch_bounds__(256) void k_agg64(const ushort* __restrict__ h,
                                               const int* __restrict__ cnt,
                                               const ushort* __restrict__ slot,
                                               const float* __restrict__ bias,
                                               const int* __restrict__ ovfcnt,
                                               const int2* __restrict__ ovf,
                                               float* __restrict__ out, int n) {
    int node = (blockIdx.x * 256 + threadIdx.x) >> 6;
    int lane = threadIdx.x & 63;
    if (node >= n) return;
    int deg = cnt[node];
    int degm = min(deg, CAP);
    float isd_i = rsqrtf((float)(deg + 1));
    int sidx = (int)__builtin_nontemporal_load(slot + (size_t)node * CAP + lane);

    const int g = lane >> 3;          // 0..7
    const int i = lane & 7;           // 0..7
    const ushort* hp = h + 8 * i;

    float acc[8] = {};
    for (int j = 0; j < degm; j += 16) {         // 16 edges per iter, 2 gathers
        int j0 = j + g;
        int j1 = j + 8 + g;
        int   s0 = __shfl(sidx, j0);
        int   s1 = __shfl(sidx, j1);
        float w0 = (j0 < degm) ? 1.f : 0.f;
        float w1 = (j1 < degm) ? 1.f : 0.f;
        uint4 v0 = *(const uint4*)(hp + (size_t)s0 * 64);
        uint4 v1 = *(const uint4*)(hp + (size_t)s1 * 64);
        acc[0] += w0 * bf2f_lo(v0.x) + w1 * bf2f_lo(v1.x);
        acc[1] += w0 * bf2f_hi(v0.x) + w1 * bf2f_hi(v1.x);
        acc[2] += w0 * bf2f_lo(v0.y) + w1 * bf2f_lo(v1.y);
        acc[3] += w0 * bf2f_hi(v0.y) + w1 * bf2f_hi(v1.y);
        acc[4] += w0 * bf2f_lo(v0.z) + w1 * bf2f_lo(v1.z);
        acc[5] += w0 * bf2f_hi(v0.z) + w1 * bf2f_hi(v1.z);
        acc[6] += w0 * bf2f_lo(v0.w) + w1 * bf2f_lo(v1.w);
        acc[7] += w0 * bf2f_hi(v0.w) + w1 * bf2f_hi(v1.w);
    }
    int ovn = *ovfcnt;
    for (int t = 0; t < ovn; ++t) {
        int2 p = ovf[t];
        if (p.x == node && g == 0) {
            uint4 v0 = *(const uint4*)(hp + (size_t)p.y * 64);
            acc[0] += bf2f_lo(v0.x); acc[1] += bf2f_hi(v0.x);
            acc[2] += bf2f_lo(v0.y); acc[3] += bf2f_hi(v0.y);
            acc[4] += bf2f_lo(v0.z); acc[5] += bf2f_hi(v0.z);
            acc[6] += bf2f_lo(v0.w); acc[7] += bf2f_hi(v0.w);
        }
    }
    #pragma unroll
    for (int k = 0; k < 8; ++k) {                // fold octs
        acc[k] += __shfl_xor(acc[k], 8);
        acc[k] += __shfl_xor(acc[k], 16);
        acc[k] += __shfl_xor(acc[k], 32);
    }
    if (g == 0) {
        uint4 vs = *(const uint4*)(hp + (size_t)node * 64);   // scaled self
        float4 ba = *(const float4*)(bias + 8 * i);
        float4 bb = *(const float4*)(bias + 8 * i + 4);
        float4 r0, r1;
        r0.x = (acc[0] + bf2f_lo(vs.x)) * isd_i + ba.x;
        r0.y = (acc[1] + bf2f_hi(vs.x)) * isd_i + ba.y;
        r0.z = (acc[2] + bf2f_lo(vs.y)) * isd_i + ba.z;
        r0.w = (acc[3] + bf2f_hi(vs.y)) * isd_i + ba.w;
        r1.x = (acc[4] + bf2f_lo(vs.z)) * isd_i + bb.x;
        r1.y = (acc[5] + bf2f_hi(vs.z)) * isd_i + bb.y;
        r1.z = (acc[6] + bf2f_lo(vs.w)) * isd_i + bb.z;
        r1.w = (acc[7] + bf2f_hi(vs.w)) * isd_i + bb.w;
        float* op = out + (size_t)node * 64 + 8 * i;
        *(float4*)op = r0;
        *(float4*)(op + 4) = r1;
    }
}

static inline size_t align256(size_t x) { return (x + 255) & ~(size_t)255; }

extern "C" void kernel_launch(void* const* d_in, const int* in_sizes, int n_in,
                              void* d_out, int out_size, void* d_ws, size_t ws_size,
                              hipStream_t stream) {
    const float* x  = (const float*)d_in[0];
    const int*   ei = (const int*)d_in[1];
    const float* W1 = (const float*)d_in[2];
    const float* b1 = (const float*)d_in[3];
    const float* W2 = (const float*)d_in[4];
    const float* b2 = (const float*)d_in[5];
    float* out = (float*)d_out;

    const int N = in_sizes[0] / GCN_IN;   // 50000
    const int E = in_sizes[1] / 2;        // 800000
    const int* src = ei;
    const int* dst = ei + E;

    char* ws = (char*)d_ws;
    size_t o = 0;
    int*    cnt    = (int*)(ws + o);     o += align256((size_t)N * 4);
    int*    ovfcnt = (int*)(ws + o);     o += 256;
    int2*   ovf    = (int2*)(ws + o);    o += align256((size_t)OVF_CAP * 8);
    ushort* slot   = (ushort*)(ws + o);  o += align256((size_t)N * CAP * 2);
    ushort* hb     = (ushort*)(ws + o);  o += align256((size_t)N * GCN_H * 2);
    ushort* h1b    = (ushort*)(ws + o);  o += align256((size_t)N * GCN_H * 2);
    ushort* h2b    = (ushort*)(ws + o);  o += align256((size_t)N * GCN_OUT * 2);

    // zero cnt + ovfcnt (contiguous)
    hipMemsetAsync(cnt, 0, align256((size_t)N * 4) + 256, stream);

    // 1. XCD-partitioned scatter (slot window L2-resident)
    k_scatter<<<SCAT_BLOCKS, 256, 0, stream>>>(src, dst, cnt, slot,
                                               ovfcnt, ovf, E, N);

    // 2. MFMA GEMM1: x @ W1 -> hb (bf16, isd-scaled epilogue)
    k_gemm1<<<(N + 63) / 64, 256, 0, stream>>>(x, W1, cnt, hb, N);

    // 3. agg layer 1 -> h1b (bf16)
    k_agg128<<<(N * 64 + 255) / 256, 256, 0, stream>>>(hb, cnt, slot, b1,
                                                       ovfcnt, ovf, h1b, N);
    // 4. MFMA GEMM2: h1b @ W2 -> h2b (bf16, isd-scaled epilogue)
    k_gemm2<<<(N + 63) / 64, 256, 0, stream>>>(h1b, W2, cnt, h2b, N);

    // 5. agg layer 2 -> out (fp32)
    k_agg64<<<(N * 64 + 255) / 256, 256, 0, stream>>>(h2b, cnt, slot, b2,
                                                      ovfcnt, ovf, out, N);
}